// Round 9
// baseline (233.598 us; speedup 1.0000x reference)
//
#include <hip/hip_runtime.h>
#include <math.h>

namespace {
constexpr int BB = 32;
constexpr int NN = 1024;
constexpr int ET = 16;
constexpr int HH = 64;
constexpr int CIN = 65;       // Din + HID
constexpr int KI = 2*CIN;     // 130
constexpr int COG = 2*HH;     // 128
constexpr int COU = HH;       // 64
constexpr int PP = 288;
constexpr int FF = 7;
constexpr int FRQ = 12;
constexpr int XK = 160;       // padded K for MFMA (5 x 32)

typedef __attribute__((ext_vector_type(4))) float f32x4;
typedef __attribute__((ext_vector_type(8))) short s16x8;
typedef unsigned long long ull;

__device__ __forceinline__ float bf2f(unsigned short u) {
    unsigned v = ((unsigned)u) << 16;
    return __builtin_bit_cast(float, v);
}
__device__ __forceinline__ unsigned short f2bf(float f) {
    unsigned u = __builtin_bit_cast(unsigned, f);
    u += 0x7fffu + ((u >> 16) & 1u);   // RNE
    return (unsigned short)(u >> 16);
}
__device__ __forceinline__ unsigned cvtpk(float lo, float hi) {
    unsigned r;
    asm("v_cvt_pk_bf16_f32 %0, %1, %2" : "=v"(r) : "v"(lo), "v"(hi));
    return r;
}
__device__ __forceinline__ float ldany(const float* p) { return *p; }
__device__ __forceinline__ float ldany(const unsigned short* p) { return bf2f(*p); }

// ---------------- prep kernels ----------------
__global__ void k_prep1(const float* __restrict__ SE, const float* __restrict__ Wse,
                        const float* __restrict__ bse, const float* __restrict__ Ttod,
                        const float* __restrict__ Tdow, const int* __restrict__ tidx,
                        float* __restrict__ se, float* __restrict__ tt) {
    int idx = blockIdx.x*blockDim.x + threadIdx.x;
    if (idx < NN*ET) {
        int n = idx / ET, d = idx % ET;
        float acc = bse[d];
        #pragma unroll
        for (int e = 0; e < ET; ++e) acc += SE[n*ET + e]*Wse[e*ET + d];
        se[idx] = acc;
    } else if (idx < NN*ET + BB*ET) {
        int r = idx - NN*ET;
        int b = r / ET, d = r % ET;
        int t = tidx[b]*FRQ;
        tt[r] = Ttod[(t % PP)*ET + d] + Tdow[((t/PP) % FF)*ET + d];
    }
}

// fused: stebf build + Wpool bf16-transpose (independent outputs, one launch)
__global__ void k_prep2(const float* __restrict__ se, const float* __restrict__ tt,
                        const float* __restrict__ Wg, const float* __restrict__ Wu,
                        unsigned short* __restrict__ stebf,
                        unsigned short* __restrict__ Wptg, unsigned short* __restrict__ Wptu) {
    int idx = blockIdx.x*blockDim.x + threadIdx.x;
    if (idx < BB*NN*ET) {
        int d = idx % ET;
        int n = (idx/ET) % NN;
        int b = idx/(ET*NN);
        stebf[idx] = f2bf(se[n*ET+d] + tt[b*ET+d]);
        return;
    }
    idx -= BB*NN*ET;
    if (idx < ET*COG*XK) {
        int d = idx/(COG*XK), r = idx%(COG*XK), o = r/XK, ki = r%XK;
        float v = (ki < KI) ? Wg[((size_t)d*KI + ki)*COG + o] : 0.f;
        Wptg[((size_t)d*COG + o)*XK + ki] = f2bf(v);
        return;
    }
    idx -= ET*COG*XK;
    if (idx < ET*COU*XK) {
        int d = idx/(COU*XK), r = idx%(COU*XK), o = r/XK, ki = r%XK;
        float v = (ki < KI) ? Wu[((size_t)d*KI + ki)*COU + o] : 0.f;
        Wptu[((size_t)d*COU + o)*XK + ki] = f2bf(v);
    }
}

// fused: V transpose (vt) + xg pack cols 0..64 / zero 130..159
template<typename T>
__global__ void k_vin(const float* __restrict__ x, const T* __restrict__ sv,
                      unsigned short* __restrict__ xgbf, unsigned short* __restrict__ vt) {
    int idx = blockIdx.x*blockDim.x + threadIdx.x;
    if (idx < BB*128*64) {
        int och = idx & 63, mb = (idx >> 6) & 127, b = idx >> 13;
        const T* src = sv + ((size_t)b*NN + mb*8)*HH + och;
        float v0=ldany(src), v1=ldany(src+HH), v2=ldany(src+2*HH), v3=ldany(src+3*HH);
        float v4=ldany(src+4*HH), v5=ldany(src+5*HH), v6=ldany(src+6*HH), v7=ldany(src+7*HH);
        ull lo = (ull)f2bf(v0) | ((ull)f2bf(v1)<<16) | ((ull)f2bf(v2)<<32) | ((ull)f2bf(v3)<<48);
        ull hi = (ull)f2bf(v4) | ((ull)f2bf(v5)<<16) | ((ull)f2bf(v6)<<32) | ((ull)f2bf(v7)<<48);
        ull* dst = (ull*)(vt + (size_t)idx*8);
        dst[0] = lo; dst[1] = hi;
        return;
    }
    idx -= BB*128*64;
    if (idx >= BB*NN*(XK/2)) return;
    int row = idx/(XK/2), c = idx%(XK/2);
    if (c < 32) {
        int k0 = 2*c;
        float v0 = (k0 == 0) ? x[row] : ldany(sv + (size_t)row*HH + k0 - 1);
        float v1 = ldany(sv + (size_t)row*HH + k0);
        ((unsigned*)xgbf)[(size_t)row*(XK/2) + c] = ((unsigned)f2bf(v1) << 16) | f2bf(v0);
    } else if (c == 32) {
        xgbf[(size_t)row*XK + 64] = f2bf(ldany(sv + (size_t)row*HH + 63));
    } else if (c >= 65) {
        ((unsigned*)xgbf)[(size_t)row*(XK/2) + c] = 0;
    }
}

// ---------------- fused attention pass ----------------
constexpr int SSTR   = 1048;       // 524 dwords = 12 mod 32
constexpr int S_OFF  = 0;          // 16*1048*2 = 33536
constexpr int XV_OFF = 33536;      // 4096
constexpr int MSH_OFF  = 37632;    // 256
constexpr int MSHC_OFF = 37888;    // 64
constexpr int LP_OFF   = 37952;    // 256
constexpr int AXP_OFF  = 38208;    // 256
constexpr int LSH_OFF  = 38464;    // 64
constexpr int SMEM_BYTES = 38528;  // 4 blocks/CU

// Swapped-operand scores: A = STE cols (per j), B = STE rows (hoisted).
// Thread (w,g,c15) holds S[row=c15][col = j*64 + w*16 + g*4 + q], q=0..3
// -> packed b64 LDS writes, scalar per-thread max/L/ax (row-local).
template<int PASS>
__global__ __launch_bounds__(256, 4) void k_attn(
    const unsigned short* __restrict__ stebf, const float* __restrict__ Rg,
    const float* __restrict__ SCg, const float* __restrict__ xg,
    const unsigned short* __restrict__ vt,
    float* __restrict__ Mr, float* __restrict__ Li,
    unsigned short* __restrict__ xgout)
{
    extern __shared__ char smem[];
    const int t = threadIdx.x, lane = t & 63, w = t >> 6;
    const int c15 = lane & 15, g = lane >> 4;
    const int strip = blockIdx.x, b = blockIdx.y;
    const size_t bN = (size_t)b * NN;
    const int r0 = strip * 16;

    float* Mshf  = (float*)(smem + MSH_OFF);
    float* MshCf = (float*)(smem + MSHC_OFF);
    float* Lpf   = (float*)(smem + LP_OFF);
    float* Axpf  = (float*)(smem + AXP_OFF);
    float* Lshf  = (float*)(smem + LSH_OFF);

    if (PASS == 1) {
        ((float4*)(smem + XV_OFF))[t] = ((const float4*)(xg + bN))[t];
    } else {
        if (t < 16) Lshf[t] = Li[bN + r0 + t];
    }
    float mp2 = 0.f;
    if (PASS == 2) mp2 = Mr[bN + r0 + c15];

    // ---- scores (+ exp for PASS2) ----
    float mx = -INFINITY;
    {
        s16x8 bfr = {0,0,0,0,0,0,0,0};
        if (g < 2) bfr = *(const s16x8*)(stebf + (bN + r0 + c15)*ET + g*8);
        const float* Rb  = Rg  + (bN + r0 + c15)*NN;
        const float* SCb = SCg + (size_t)(r0 + c15)*NN;
        const int colq = w*16 + g*4;
        float4 rc = *(const float4*)(Rb + colq);
        float4 sc = *(const float4*)(SCb + colq);
        for (int j = 0; j < 16; ++j) {
            s16x8 af = {0,0,0,0,0,0,0,0};
            if (g < 2) af = *(const s16x8*)(stebf + (bN + j*64 + w*16 + c15)*ET + g*8);
            float4 rn = {0,0,0,0}, sn = {0,0,0,0};
            if (j < 15) {
                rn = *(const float4*)(Rb + colq + (j+1)*64);
                sn = *(const float4*)(SCb + colq + (j+1)*64);
            }
            f32x4 zero = {0.f,0.f,0.f,0.f};
            f32x4 d = __builtin_amdgcn_mfma_f32_16x16x32_bf16(af, bfr, zero, 0, 0, 0);
            float s0 = fmaxf(d[0],0.f) + rc.x + sc.x;
            float s1 = fmaxf(d[1],0.f) + rc.y + sc.y;
            float s2 = fmaxf(d[2],0.f) + rc.z + sc.z;
            float s3 = fmaxf(d[3],0.f) + rc.w + sc.w;
            unsigned byteo = (unsigned)(c15*SSTR + j*64 + colq)*2u;
            if (PASS == 1) {
                mx = fmaxf(mx, fmaxf(fmaxf(s0,s1), fmaxf(s2,s3)));
                *(ull*)(smem + S_OFF + byteo) = (ull)cvtpk(s0,s1) | ((ull)cvtpk(s2,s3) << 32);
            } else {
                float p0 = __expf(s0 - mp2), p1 = __expf(s1 - mp2);
                float p2 = __expf(s2 - mp2), p3 = __expf(s3 - mp2);
                *(ull*)(smem + S_OFF + byteo) = (ull)cvtpk(p0,p1) | ((ull)cvtpk(p2,p3) << 32);
            }
            rc = rn; sc = sn;
        }
    }

    if (PASS == 1) {
        mx = fmaxf(mx, __shfl_xor(mx, 16));
        mx = fmaxf(mx, __shfl_xor(mx, 32));
        if (lane < 16) Mshf[w*16 + c15] = mx;
        __syncthreads();
        if (t < 16) {
            float M = fmaxf(fmaxf(Mshf[t], Mshf[16+t]), fmaxf(Mshf[32+t], Mshf[48+t]));
            MshCf[t] = M;
            Mr[bN + r0 + t] = M;
        }
        __syncthreads();
        // sweep own S -> P, accumulate L and ax
        const float m = MshCf[c15];
        const int colq = w*16 + g*4;
        float L = 0.f, ax = 0.f;
        for (int it = 0; it < 16; ++it) {
            unsigned byteo = (unsigned)(c15*SSTR + it*64 + colq)*2u;
            ull v = *(ull*)(smem + S_OFF + byteo);
            float s0 = bf2f((unsigned short)v);
            float s1 = bf2f((unsigned short)(v >> 16));
            float s2 = bf2f((unsigned short)(v >> 32));
            float s3 = bf2f((unsigned short)(v >> 48));
            float p0 = __expf(s0-m), p1 = __expf(s1-m), p2 = __expf(s2-m), p3 = __expf(s3-m);
            float4 xq = *(const float4*)(smem + XV_OFF + (it*64 + colq)*4);
            L += (p0 + p1) + (p2 + p3);
            ax += p0*xq.x + p1*xq.y + p2*xq.z + p3*xq.w;
            *(ull*)(smem + S_OFF + byteo) = (ull)cvtpk(p0,p1) | ((ull)cvtpk(p2,p3) << 32);
        }
        L += __shfl_xor(L, 16); L += __shfl_xor(L, 32);
        ax += __shfl_xor(ax, 16); ax += __shfl_xor(ax, 32);
        if (lane < 16) { Lpf[w*16 + c15] = L; Axpf[w*16 + c15] = ax; }
        __syncthreads();
        if (t < 16) {
            float Lt = Lpf[t] + Lpf[16+t] + Lpf[32+t] + Lpf[48+t];
            float li = 1.f / Lt;
            Lshf[t] = li;
            Li[bN + r0 + t] = li;
            float axt = Axpf[t] + Axpf[16+t] + Axpf[32+t] + Axpf[48+t];
            xgout[(bN + r0 + t)*XK + 65] = f2bf(axt * li);
        }
        __syncthreads();
    } else {
        __syncthreads();   // P writes + Lshf staging visible to all
    }

    {   // ---- PV via MFMA; A = P rows from LDS, B = vt from global ----
        f32x4 acc = {0.f,0.f,0.f,0.f};
        const unsigned short* vtb = vt + ((size_t)b*128*64 + (w*16 + c15))*8;
        #pragma unroll 4
        for (int j = 0; j < 16; ++j) {
            #pragma unroll
            for (int ks = 0; ks < 2; ++ks) {
                s16x8 a  = *(const s16x8*)(smem + S_OFF + (unsigned)(c15*SSTR + j*64 + ks*32 + g*8)*2u);
                s16x8 bv = *(const s16x8*)(vtb + (size_t)(j*8 + ks*4 + g)*512);
                acc = __builtin_amdgcn_mfma_f32_16x16x32_bf16(a, bv, acc, 0, 0, 0);
            }
        }
        #pragma unroll
        for (int q = 0; q < 4; ++q) {
            int rowl = g*4 + q;
            float li = Lshf[rowl];
            xgout[(bN + r0 + rowl)*XK + 66 + w*16 + c15] = f2bf(acc[q] * li);
        }
    }
}

// ---------------- fused avwgcn-apply ----------------
template<int COUT, int EPI>   // EPI 0: gate (sigmoid -> zs,r), 1: upd (tanh -> out)
__global__ __launch_bounds__(256, 2) void k_apply(
    const unsigned short* __restrict__ Wpt, const float* __restrict__ bias,
    const unsigned short* __restrict__ stebf, const unsigned short* __restrict__ xgbf,
    const float* __restrict__ state, unsigned short* __restrict__ zsbf,
    unsigned short* __restrict__ rrbf, float* __restrict__ out)
{
    const int t = threadIdx.x, lane = t & 63, w = t >> 6;
    const int c15 = lane & 15, g = lane >> 4;
    const int n0 = blockIdx.x*32, b = blockIdx.y, oh = blockIdx.z;
    const int o = oh*64 + w*16 + c15;

    f32x4 acc[16][2];
    #pragma unroll
    for (int d = 0; d < 16; ++d) {
        acc[d][0] = (f32x4){0.f,0.f,0.f,0.f};
        acc[d][1] = (f32x4){0.f,0.f,0.f,0.f};
    }

    const unsigned short* Ar0 = xgbf + ((size_t)b*NN + n0 + c15)*XK + g*8;
    const unsigned short* Ar1 = Ar0 + (size_t)16*XK;
    const unsigned short* Bp  = Wpt + (size_t)o*XK + g*8;

    for (int ks = 0; ks < 5; ++ks) {
        s16x8 a0 = *(const s16x8*)(Ar0 + ks*32);
        s16x8 a1 = *(const s16x8*)(Ar1 + ks*32);
        #pragma unroll
        for (int d = 0; d < 16; ++d) {
            s16x8 bf = *(const s16x8*)(Bp + (size_t)d*COUT*XK + ks*32);
            acc[d][0] = __builtin_amdgcn_mfma_f32_16x16x32_bf16(a0, bf, acc[d][0], 0, 0, 0);
            acc[d][1] = __builtin_amdgcn_mfma_f32_16x16x32_bf16(a1, bf, acc[d][1], 0, 0, 0);
        }
    }

    float biasv[16];
    #pragma unroll
    for (int d = 0; d < 16; ++d) biasv[d] = bias[d*COUT + o];

    #pragma unroll
    for (int mt = 0; mt < 2; ++mt) {
        #pragma unroll
        for (int q = 0; q < 4; ++q) {
            int n = n0 + mt*16 + g*4 + q;
            size_t bn = (size_t)b*NN + n;
            const ull* sp = (const ull*)(stebf + bn*ET);
            float val = 0.f;
            #pragma unroll
            for (int dd = 0; dd < 4; ++dd) {
                ull sv4 = sp[dd];
                float s0 = bf2f((unsigned short)sv4);
                float s1 = bf2f((unsigned short)(sv4 >> 16));
                float s2 = bf2f((unsigned short)(sv4 >> 32));
                float s3 = bf2f((unsigned short)(sv4 >> 48));
                val += s0*(acc[dd*4+0][mt][q] + biasv[dd*4+0]);
                val += s1*(acc[dd*4+1][mt][q] + biasv[dd*4+1]);
                val += s2*(acc[dd*4+2][mt][q] + biasv[dd*4+2]);
                val += s3*(acc[dd*4+3][mt][q] + biasv[dd*4+3]);
            }
            if (EPI == 0) {
                float gv = 1.f/(1.f + __expf(-val));
                if (oh == 0) zsbf[bn*HH + o] = f2bf(gv * state[bn*HH + o]);
                else         rrbf[bn*HH + (o - 64)] = f2bf(gv);
            } else {
                float hc = tanhf(val);
                float rv = bf2f(rrbf[bn*HH + o]);
                out[bn*HH + o] = rv*state[bn*HH + o] + (1.f - rv)*hc;
            }
        }
    }
}

} // namespace

extern "C" void kernel_launch(void* const* d_in, const int* in_sizes, int n_in,
                              void* d_out, int out_size, void* d_ws, size_t ws_size,
                              hipStream_t stream) {
    const float* x     = (const float*)d_in[0];
    const float* R     = (const float*)d_in[1];
    const float* state = (const float*)d_in[2];
    const float* SC    = (const float*)d_in[3];
    const float* SE    = (const float*)d_in[4];
    const float* W_se  = (const float*)d_in[5];
    const float* b_se  = (const float*)d_in[6];
    const float* T_tod = (const float*)d_in[7];
    const float* T_dow = (const float*)d_in[8];
    const float* W_g   = (const float*)d_in[9];
    const float* b_g   = (const float*)d_in[10];
    const float* W_u   = (const float*)d_in[11];
    const float* b_u   = (const float*)d_in[12];
    const int*   tidx  = (const int*)d_in[13];
    float* out = (float*)d_out;
    float* ws = (float*)d_ws;

    // ~25 MB total
    float* se = ws;                                       // 16384 f
    float* tt = se + 16384;                               // 512 f
    float* Mr = tt + 512;                                 // 32768 f
    float* Li = Mr + 32768;                               // 32768 f
    unsigned short* stebf = (unsigned short*)(Li + 32768);// 524288 us
    unsigned short* xgbf  = stebf + 524288;               // 5242880 us
    unsigned short* zsbf  = xgbf + 5242880;               // 2097152 us
    unsigned short* rrbf  = zsbf + 2097152;               // 2097152 us
    unsigned short* vt    = rrbf + 2097152;               // 2097152 us
    unsigned short* Wptg  = vt + 2097152;                 // 327680 us
    unsigned short* Wptu  = Wptg + 327680;                // 163840 us

    k_prep1<<<66, 256, 0, stream>>>(SE, W_se, b_se, T_tod, T_dow, tidx, se, tt);
    k_prep2<<<3968, 256, 0, stream>>>(se, tt, W_g, W_u, stebf, Wptg, Wptu);

    k_vin<float><<<11264, 256, 0, stream>>>(x, state, xgbf, vt);
    k_attn<1><<<dim3(64, 32), 256, SMEM_BYTES, stream>>>(
        stebf, R, SC, x, vt, Mr, Li, xgbf);
    k_apply<COG, 0><<<dim3(32, 32, 2), 256, 0, stream>>>(
        Wptg, b_g, stebf, xgbf, state, zsbf, rrbf, nullptr);

    k_vin<unsigned short><<<11264, 256, 0, stream>>>(x, zsbf, xgbf, vt);
    k_attn<2><<<dim3(64, 32), 256, SMEM_BYTES, stream>>>(
        stebf, R, SC, x, vt, Mr, Li, xgbf);
    k_apply<COU, 1><<<dim3(32, 32, 1), 256, 0, stream>>>(
        Wptu, b_u, stebf, xgbf, state, zsbf, rrbf, out);
}